// Round 5
// baseline (185.172 us; speedup 1.0000x reference)
//
#include <hip/hip_runtime.h>

// Problem: N=65536 rows, C=100 classes, 6 matrices (outputs1..5, mimic).
// out[0]            = max over ALL elements of outputs1..5
// out[1 + row*6 + j]= softmax_j(margins(row)/TEMP), TEMP=2
// margin(x,t) = (x[t] == max(x)) ? max(x) - second_max(x) : 0
//
// R12: R11's named-register MLP experiment was VOID - compiler re-sank the
// loads (VGPR_Count stayed 32). This round forces it with raw inline-asm
// global_load_dwordx4: 13 loads against one base addr (imm offsets 0..192),
// outputs in 13 named f32x4 regs (52 forced-live VGPRs), then ONE
// s_waitcnt vmcnt(0) + sched_barrier(0) (guide rule #18) before the reduce.
// Pure A/B vs R0/R11 on load schedule only; VGPR_Count is the ran-or-not
// check. If dur unchanged, per-CU miss-service wall confirmed -> roofline.

constexpr int C = 100;
constexpr float INV_TEMP = 0.5f;   // 1/TEMP

typedef float f32x4 __attribute__((ext_vector_type(4)));

// Order-preserving float -> unsigned encoding for atomicMax.
// enc(f) >= enc(-inf) = 0x007FFFFF > 0, so memset-0 is a valid identity.
__device__ __forceinline__ unsigned enc_f(float f) {
    unsigned u = __float_as_uint(f);
    return (u & 0x80000000u) ? ~u : (u | 0x80000000u);
}

__device__ __forceinline__ void t2(float& m1, float& m2, float v) {
    m2 = fmaxf(m2, fminf(m1, v));
    m1 = fmaxf(m1, v);
}

#define GLOAD(dst, base, OFF) \
    asm volatile("global_load_dwordx4 %0, %1, off offset:" #OFF \
                 : "=v"(dst) : "v"(base))

// Grid: (ceil(2n/256), 6). Block: 256 threads. Thread = (row, half, matrix).
__global__ __launch_bounds__(256, 6) void margin_kernel(
    const float* __restrict__ o1, const float* __restrict__ o2,
    const float* __restrict__ o3, const float* __restrict__ o4,
    const float* __restrict__ o5, const float* __restrict__ mimic,
    const int* __restrict__ tgt, float* __restrict__ out,
    unsigned* __restrict__ ws, int n)
{
    __shared__ unsigned wmax[4];

    const int m    = blockIdx.y;                       // 0..5 (uniform)
    const int tid2 = blockIdx.x * 256 + threadIdx.x;
    const int row  = tid2 >> 1;                        // partner pair = lanes 2k,2k+1
    const int half = tid2 & 1;                         // 0: f4[0,13), 1: f4[13,25)
    const int lane = threadIdx.x & 63;

    const float* __restrict__ mat =
        (m == 0) ? o1 : (m == 1) ? o2 : (m == 2) ? o3 :
        (m == 3) ? o4 : (m == 4) ? o5 : mimic;

    // int32-vs-int64 target layout detection (wave-uniform).
    // int64 little-endian nonneg => odd 32-bit words all zero.
    const int pidx  = 2 * lane + 1;
    const int probe = (pidx < n) ? tgt[pidx] : 0;
    const unsigned long long nz = __ballot(probe != 0);
    const int tstride = (nz == 0ull) ? 2 : 1;

    float rowM1 = -INFINITY;   // post-merge row max (for global max reduce)

    if (row < n) {             // partner lanes agree on this predicate
        const size_t rowoff = (size_t)row * C;
        const f32x4* p4 = (const f32x4*)(mat + rowoff) + (half ? 13 : 0);
        // 13th f4 exists only for half 0; half 1 loads a safe in-row dummy.
        const f32x4* p12 = half ? p4 : (p4 + 12);

        // ---- 13 forced-parallel loads: one vmcnt queue, 52 live VGPRs ----
        f32x4 v0, v1, v2, v3, v4, v5, v6, v7, v8, v9, v10, v11, v12;
        GLOAD(v0,  p4, 0);
        GLOAD(v1,  p4, 16);
        GLOAD(v2,  p4, 32);
        GLOAD(v3,  p4, 48);
        GLOAD(v4,  p4, 64);
        GLOAD(v5,  p4, 80);
        GLOAD(v6,  p4, 96);
        GLOAD(v7,  p4, 112);
        GLOAD(v8,  p4, 128);
        GLOAD(v9,  p4, 144);
        GLOAD(v10, p4, 160);
        GLOAD(v11, p4, 176);
        GLOAD(v12, p12, 0);
        asm volatile("s_waitcnt vmcnt(0)" ::: "memory");
        __builtin_amdgcn_sched_barrier(0);
        if (half) v12 = f32x4{-INFINITY, -INFINITY, -INFINITY, -INFINITY};

        // ---- 4 independent top-2 trackers (ILP on the fmax chains) ----
        float m1x = -INFINITY, m2x = -INFINITY;
        float m1y = -INFINITY, m2y = -INFINITY;
        float m1z = -INFINITY, m2z = -INFINITY;
        float m1w = -INFINITY, m2w = -INFINITY;
        t2(m1x,m2x,v0.x);  t2(m1y,m2y,v0.y);  t2(m1z,m2z,v0.z);  t2(m1w,m2w,v0.w);
        t2(m1x,m2x,v1.x);  t2(m1y,m2y,v1.y);  t2(m1z,m2z,v1.z);  t2(m1w,m2w,v1.w);
        t2(m1x,m2x,v2.x);  t2(m1y,m2y,v2.y);  t2(m1z,m2z,v2.z);  t2(m1w,m2w,v2.w);
        t2(m1x,m2x,v3.x);  t2(m1y,m2y,v3.y);  t2(m1z,m2z,v3.z);  t2(m1w,m2w,v3.w);
        t2(m1x,m2x,v4.x);  t2(m1y,m2y,v4.y);  t2(m1z,m2z,v4.z);  t2(m1w,m2w,v4.w);
        t2(m1x,m2x,v5.x);  t2(m1y,m2y,v5.y);  t2(m1z,m2z,v5.z);  t2(m1w,m2w,v5.w);
        t2(m1x,m2x,v6.x);  t2(m1y,m2y,v6.y);  t2(m1z,m2z,v6.z);  t2(m1w,m2w,v6.w);
        t2(m1x,m2x,v7.x);  t2(m1y,m2y,v7.y);  t2(m1z,m2z,v7.z);  t2(m1w,m2w,v7.w);
        t2(m1x,m2x,v8.x);  t2(m1y,m2y,v8.y);  t2(m1z,m2z,v8.z);  t2(m1w,m2w,v8.w);
        t2(m1x,m2x,v9.x);  t2(m1y,m2y,v9.y);  t2(m1z,m2z,v9.z);  t2(m1w,m2w,v9.w);
        t2(m1x,m2x,v10.x); t2(m1y,m2y,v10.y); t2(m1z,m2z,v10.z); t2(m1w,m2w,v10.w);
        t2(m1x,m2x,v11.x); t2(m1y,m2y,v11.y); t2(m1z,m2z,v11.z); t2(m1w,m2w,v11.w);
        t2(m1x,m2x,v12.x); t2(m1y,m2y,v12.y); t2(m1z,m2z,v12.z); t2(m1w,m2w,v12.w);

        // merge 4 trackers -> this thread's (tm1, tm2)
        const float m1xy = fmaxf(m1x, m1y);
        const float m2xy = fmaxf(fminf(m1x, m1y), fmaxf(m2x, m2y));
        const float m1zw = fmaxf(m1z, m1w);
        const float m2zw = fmaxf(fminf(m1z, m1w), fmaxf(m2z, m2w));
        const float tm1  = fmaxf(m1xy, m1zw);
        const float tm2  = fmaxf(fminf(m1xy, m1zw), fmaxf(m2xy, m2zw));

        // merge with partner (lane^1; halves are disjoint -> exact)
        const float p1 = __shfl_xor(tm1, 1);
        const float p2 = __shfl_xor(tm2, 1);
        const float M1 = fmaxf(tm1, p1);
        const float M2 = fmaxf(fminf(tm1, p1), fmaxf(tm2, p2));

        const int   t  = tgt[(size_t)row * tstride];   // 0..99 (both partners)
        const float tv = mat[rowoff + t];              // L1-hit, same value both
        if (!half)
            out[1 + (size_t)row * 6 + m] = (tv == M1) ? (M1 - M2) * INV_TEMP : 0.0f;
        rowM1 = M1;
    }

    // global max over matrices 0..4: wave reduce, 4-slot LDS, 1 atomic/block
    #pragma unroll
    for (int s = 1; s < 64; s <<= 1) rowM1 = fmaxf(rowM1, __shfl_xor(rowM1, s));
    if (m < 5) {                                  // block-uniform branch
        if (lane == 0) wmax[threadIdx.x >> 6] = enc_f(rowM1);
        __syncthreads();
        if (threadIdx.x == 0) {
            const unsigned u = max(max(wmax[0], wmax[1]), max(wmax[2], wmax[3]));
            atomicMax(ws, u);
        }
    }
}

// In-place 6-wide softmax over out[1+row*6 .. +5]; thread 0 decodes out[0].
__global__ __launch_bounds__(256) void softmax_kernel(
    float* __restrict__ out, const unsigned* __restrict__ ws, int n)
{
    const int row = blockIdx.x * blockDim.x + threadIdx.x;
    if (row < n) {
        float* p = out + 1 + (size_t)row * 6;
        float mrg[6];
        #pragma unroll
        for (int j = 0; j < 6; ++j) mrg[j] = p[j];
        float mx = mrg[0];
        #pragma unroll
        for (int j = 1; j < 6; ++j) mx = fmaxf(mx, mrg[j]);
        float e[6], s = 0.0f;
        #pragma unroll
        for (int j = 0; j < 6; ++j) { e[j] = __expf(mrg[j] - mx); s += e[j]; }
        const float inv = 1.0f / s;
        #pragma unroll
        for (int j = 0; j < 6; ++j) p[j] = e[j] * inv;
    }
    if (row == 0) {
        const unsigned e = ws[0];
        const unsigned bits = (e & 0x80000000u) ? (e & 0x7FFFFFFFu) : ~e;
        out[0] = __uint_as_float(bits);
    }
}

extern "C" void kernel_launch(void* const* d_in, const int* in_sizes, int n_in,
                              void* d_out, int out_size, void* d_ws, size_t ws_size,
                              hipStream_t stream) {
    const float* o1    = (const float*)d_in[0];
    const float* o2    = (const float*)d_in[1];
    const float* o3    = (const float*)d_in[2];
    const float* o4    = (const float*)d_in[3];
    const float* o5    = (const float*)d_in[4];
    const float* mimic = (const float*)d_in[5];
    const int*   tgt   = (const int*)d_in[6];
    float*       out   = (float*)d_out;
    unsigned*    ws    = (unsigned*)d_ws;

    const int n = in_sizes[6];   // N = 65536

    // ws[0] = encoded running max; 0 is the identity for the encoding.
    hipMemsetAsync(ws, 0, sizeof(unsigned), stream);

    dim3 grid((2 * n + 255) / 256, 6);   // 512 x 6 = 3072 blocks, 12288 waves
    margin_kernel<<<grid, 256, 0, stream>>>(o1, o2, o3, o4, o5, mimic,
                                            tgt, out, ws, n);
    softmax_kernel<<<(n + 255) / 256, 256, 0, stream>>>(out, ws, n);
}